// Round 7
// baseline (851.670 us; speedup 1.0000x reference)
//
#include <hip/hip_runtime.h>
#include <math.h>

#define DIM 128
#define HEADS 4
#define EPS 1e-5f
#define NBLK 1024

typedef short frag_ab __attribute__((ext_vector_type(8)));
typedef float f32x4 __attribute__((ext_vector_type(4)));
typedef unsigned short us8 __attribute__((ext_vector_type(8)));

// ---------- dtype-flex helpers ----------
__device__ __forceinline__ float us2f(unsigned short u) {
  union { unsigned int i; float f; } c; c.i = ((unsigned int)u) << 16; return c.f;
}
__device__ __forceinline__ unsigned short f2us(float f) {
  union { float ff; unsigned int i; } c; c.ff = f;
  return (unsigned short)((c.i + 0x7FFFu + ((c.i >> 16) & 1u)) >> 16);
}
__device__ __forceinline__ float ldf(const void* p, size_t i, int fl32) {
  return fl32 ? ((const float*)p)[i] : us2f(((const unsigned short*)p)[i]);
}
__device__ __forceinline__ float gelu_exact(float v) {
  return 0.5f * v * (1.0f + erff(v * 0.7071067811865475f));
}

// packed layout per row: 256 ushorts; for even c: [c*2]=xl[c], [c*2+1]=xl[c+1],
// [c*2+2]=xw[c], [c*2+3]=xw[c+1]
__device__ __forceinline__ int packed_pos(int c) { return ((c & ~1) << 1) | (c & 1); }

// ---------- dtype detection (proven) ----------
__global__ void __launch_bounds__(256)
k_detect(const unsigned short* __restrict__ x, long n, int* __restrict__ dflag) {
  long lim = n < 8192 ? n : 8192;
  int bad = 0;
  for (long i = threadIdx.x; i < lim; i += 256) {
    float v = us2f(x[i]);
    float a = fabsf(v);
    if (!(a == 0.0f || (a > 1e-30f && a < 1e3f))) bad++;
  }
  __shared__ int sb[256];
  sb[threadIdx.x] = bad;
  __syncthreads();
  for (int off = 128; off > 0; off >>= 1) {
    if ((int)threadIdx.x < off) sb[threadIdx.x] += sb[threadIdx.x + off];
    __syncthreads();
  }
  if (threadIdx.x == 0) dflag[0] = (sb[0] > 32) ? 1 : 0;
}

// ---------- CSR construction ----------
__global__ void k_deg_cnt(const int* __restrict__ dst, const void* __restrict__ ew,
                          float* __restrict__ deg, int* __restrict__ cnt,
                          int* __restrict__ rank, int E, const int* __restrict__ df) {
  const int fl32 = *df;
  int e = blockIdx.x * blockDim.x + threadIdx.x;
  if (e < E) {
    int d = dst[e];
    rank[e] = atomicAdd(&cnt[d], 1);
    float w = ldf(ew, e, fl32);
    if (isfinite(w)) atomicAdd(&deg[d], w);
  }
}

__global__ void k_dis(float* __restrict__ deg, int N) {
  int i = blockIdx.x * blockDim.x + threadIdx.x;
  if (i < N) {
    float d = deg[i];
    deg[i] = (d > 0.0f) ? rsqrtf(fmaxf(d, 1e-30f)) : 0.0f;
  }
}

__global__ void __launch_bounds__(256)
k_scan(const int* __restrict__ cnt, int* __restrict__ off, int N, int E) {
  __shared__ int part[256];
  int t = threadIdx.x;
  int chunk = (N + 255) / 256;
  int lo = t * chunk;
  int hi = lo + chunk; if (hi > N) hi = N;
  int s = 0;
  for (int i = lo; i < hi; ++i) s += cnt[i];
  part[t] = s;
  __syncthreads();
  if (t == 0) {
    int run = 0;
    for (int j = 0; j < 256; ++j) { int tmp = part[j]; part[j] = run; run += tmp; }
  }
  __syncthreads();
  int run = part[t];
  for (int i = lo; i < hi; ++i) { off[i] = run; run += cnt[i]; }
  if (t == 0) off[N] = E;
}

__global__ void k_scatter(const int* __restrict__ src, const int* __restrict__ dst,
                          const void* __restrict__ ew, const void* __restrict__ ea,
                          const float* __restrict__ dis, const int* __restrict__ off,
                          const int* __restrict__ rank, int4* __restrict__ csr,
                          int E, const int* __restrict__ df) {
  const int fl32 = *df;
  int e = blockIdx.x * blockDim.x + threadIdx.x;
  if (e >= E) return;
  int d = dst[e], s = src[e];
  int pos = off[d] + rank[e];
  float nm = dis[s] * ldf(ew, e, fl32) * dis[d];
  if (!isfinite(nm)) nm = 0.0f;
  float eav = ldf(ea, e, fl32);
  if (!isfinite(eav)) eav = 0.0f;
  csr[pos] = make_int4(s, __float_as_int(nm), __float_as_int(eav), 0);
}

// ---------- W fragment pre-shuffle (bf16 MFMA path) ----------
// Wt frag f = (kc*8+nt)*64 + lane; Wt[f*8+j] = W[kc*32 + (lane>>4)*8 + j][nt*16 + (lane&15)]
__global__ void __launch_bounds__(256)
k_prepW(const unsigned short* __restrict__ Wg, const unsigned short* __restrict__ Wl,
        unsigned short* __restrict__ Wtg, unsigned short* __restrict__ Wtl) {
  int idx = blockIdx.x * 256 + threadIdx.x;
  if (idx >= 2048) return;
  int kc = idx >> 9, rem = idx & 511, nt = rem >> 6, lane = rem & 63;
  int quad = lane >> 4, n = lane & 15;
  #pragma unroll
  for (int j = 0; j < 8; ++j) {
    int srcIdx = (kc * 32 + quad * 8 + j) * DIM + nt * 16 + n;
    Wtg[idx * 8 + j] = Wg[srcIdx];
    Wtl[idx * 8 + j] = Wl[srcIdx];
  }
}

// ---------- dual GEMM: MFMA fast path + f32 fallback; writes packed layout ----------
__global__ void __launch_bounds__(256)
k_gemm(const void* __restrict__ x, const void* __restrict__ Wg, const void* __restrict__ Wl,
       const void* __restrict__ bl, const unsigned short* __restrict__ Wtg,
       const unsigned short* __restrict__ Wtl, unsigned short* __restrict__ packed,
       int N, const int* __restrict__ df) {
  const int fl32 = *df;
  __shared__ unsigned short tiles[4][16][256];  // 32 KB
  int wid = threadIdx.x >> 6, lane = threadIdx.x & 63;
  int quad = lane >> 4, m = lane & 15;
  int row0 = blockIdx.x * 64 + wid * 16;
  if (!fl32) {
    const unsigned short* xb = (const unsigned short*)x;
    int rowm = row0 + m;
    frag_ab a[4];
    #pragma unroll
    for (int kc = 0; kc < 4; ++kc) {
      if (rowm < N) a[kc] = *(const frag_ab*)(xb + (size_t)rowm * DIM + kc * 32 + quad * 8);
      else { frag_ab z; for (int j = 0; j < 8; ++j) z[j] = 0; a[kc] = z; }
    }
    f32x4 accG[8], accL[8];
    #pragma unroll
    for (int nt = 0; nt < 8; ++nt)
      for (int r = 0; r < 4; ++r) { accG[nt][r] = 0.f; accL[nt][r] = 0.f; }
    #pragma unroll
    for (int nt = 0; nt < 8; ++nt) {
      #pragma unroll
      for (int kc = 0; kc < 4; ++kc) {
        frag_ab bg = *(const frag_ab*)(Wtg + ((size_t)(kc * 8 + nt) * 64 + lane) * 8);
        frag_ab bf = *(const frag_ab*)(Wtl + ((size_t)(kc * 8 + nt) * 64 + lane) * 8);
        accG[nt] = __builtin_amdgcn_mfma_f32_16x16x32_bf16(a[kc], bg, accG[nt], 0, 0, 0);
        accL[nt] = __builtin_amdgcn_mfma_f32_16x16x32_bf16(a[kc], bf, accL[nt], 0, 0, 0);
      }
    }
    #pragma unroll
    for (int nt = 0; nt < 8; ++nt) {
      int c = nt * 16 + m;
      float blc = us2f(((const unsigned short*)bl)[c]);
      int pos = packed_pos(c);
      #pragma unroll
      for (int r = 0; r < 4; ++r) {
        int row = quad * 4 + r;
        float vG = accG[nt][r];
        float vL = accL[nt][r] + blc;
        if (!isfinite(vG)) vG = 0.f;
        if (!isfinite(vL)) vL = 0.f;
        tiles[wid][row][pos] = f2us(vL);
        tiles[wid][row][pos + 2] = f2us(vG);
      }
    }
    __syncthreads();
    #pragma unroll
    for (int t = 0; t < 8; ++t) {
      int flat = t * 512 + lane * 8;
      int r = flat >> 8, cp = flat & 255;
      int grow = row0 + r;
      if (grow < N)
        *(us8*)(packed + (size_t)grow * 256 + cp) = *(const us8*)&tiles[wid][r][cp];
    }
  } else {
    // correctness-only f32 fallback
    int c = threadIdx.x & 127;
    float blc = ldf(bl, c, 1);
    for (int rr = (threadIdx.x >> 7); rr < 64; rr += 2) {
      int row = blockIdx.x * 64 + rr;
      if (row >= N) continue;
      float ag = 0.f, al = blc;
      for (int k = 0; k < DIM; ++k) {
        float xv = ldf(x, (size_t)row * DIM + k, 1);
        ag = fmaf(xv, ldf(Wg, k * DIM + c, 1), ag);
        al = fmaf(xv, ldf(Wl, k * DIM + c, 1), al);
      }
      if (!isfinite(ag)) ag = 0.f;
      if (!isfinite(al)) al = 0.f;
      int pos = packed_pos(c);
      packed[(size_t)row * 256 + pos] = f2us(al);
      packed[(size_t)row * 256 + pos + 2] = f2us(ag);
    }
  }
}

// ---------- MEGA: online softmax + GCN/GAT agg + LN stats ----------
__global__ void __launch_bounds__(256)
k_mega(const int* __restrict__ off, const int4* __restrict__ csr,
       const unsigned short* __restrict__ packed,
       const void* __restrict__ Wed, const void* __restrict__ att,
       const void* __restrict__ bgcn, const void* __restrict__ bgat,
       float* __restrict__ h, float* __restrict__ g,
       double* __restrict__ pA, double* __restrict__ pB, int N,
       const int* __restrict__ df) {
  const int fl32 = *df;
  int wid = threadIdx.x >> 6;
  int lane = threadIdx.x & 63;
  int node = blockIdx.x * 4 + wid;
  int c0 = lane * 2;
  float wd0 = ldf(Wed, c0, fl32), wd1 = ldf(Wed, c0 + 1, fl32);
  float at0 = ldf(att, c0, fl32), at1 = ldf(att, c0 + 1, fl32);
  double sA = 0.0, sA2 = 0.0, sB = 0.0, sB2 = 0.0;
  if (node < N) {
    int beg = off[node], end = off[node + 1];
    ushort4 xd = *(const ushort4*)(packed + (size_t)node * 256 + lane * 4);
    float xd0 = us2f(xd.x), xd1 = us2f(xd.y);
    float mx = -INFINITY, den = 0.f;
    float ga0 = 0.f, ga1 = 0.f, hc0 = 0.f, hc1 = 0.f;
    int4 cP = make_int4(0, 0, 0, 0);
    ushort4 vP = make_ushort4(0, 0, 0, 0);
    if (beg < end) {
      cP = csr[beg];
      vP = *(const ushort4*)(packed + (size_t)cP.x * 256 + lane * 4);
    }
    for (int i = beg; i < end; ++i) {
      int4 ce = cP; ushort4 v = vP;
      if (i + 1 < end) {
        cP = csr[i + 1];
        vP = *(const ushort4*)(packed + (size_t)cP.x * 256 + lane * 4);
      }
      float nm = __int_as_float(ce.y), eav = __int_as_float(ce.z);
      float vx = us2f(v.x), vy = us2f(v.y);
      float z0 = xd0 + vx + eav * wd0; z0 = (z0 > 0.f) ? z0 : 0.2f * z0;
      float z1 = xd1 + vy + eav * wd1; z1 = (z1 > 0.f) ? z1 : 0.2f * z1;
      float dot = z0 * at0 + z1 * at1;
      dot += __shfl_xor(dot, 1);
      dot += __shfl_xor(dot, 2);
      dot += __shfl_xor(dot, 4);
      dot += __shfl_xor(dot, 8);
      // single-expf online softmax: exactly one of {corr,w} is exp(-|dot-mx|)
      float e = __expf(-fabsf(dot - mx));   // first iter: exp(-inf) = 0
      bool up = dot > mx;
      float corr = up ? e : 1.0f;
      float w = up ? 1.0f : e;
      mx = up ? dot : mx;
      den = fmaf(den, corr, w);
      ga0 = fmaf(ga0, corr, w * vx);
      ga1 = fmaf(ga1, corr, w * vy);
      hc0 = fmaf(nm, us2f(v.z), hc0);
      hc1 = fmaf(nm, us2f(v.w), hc1);
    }
    float inv = (end > beg) ? 1.0f / (den + 1e-16f) : 0.0f;
    ga0 *= inv; ga1 *= inv;
    if (!isfinite(ga0)) ga0 = 0.0f;
    if (!isfinite(ga1)) ga1 = 0.0f;
    if (!isfinite(hc0)) hc0 = 0.0f;
    if (!isfinite(hc1)) hc1 = 0.0f;
    *(float2*)(h + (size_t)node * DIM + c0) = make_float2(hc0, hc1);
    *(float2*)(g + (size_t)node * DIM + c0) = make_float2(ga0, ga1);
    float hA0 = hc0 + ldf(bgcn, c0, fl32), hA1 = hc1 + ldf(bgcn, c0 + 1, fl32);
    float gB0 = ga0 + ldf(bgat, c0, fl32), gB1 = ga1 + ldf(bgat, c0 + 1, fl32);
    sA  = (double)hA0 + (double)hA1;
    sA2 = (double)hA0 * hA0 + (double)hA1 * hA1;
    sB  = (double)gB0 + (double)gB1;
    sB2 = (double)gB0 * gB0 + (double)gB1 * gB1;
  }
  __shared__ double l1[256], l2[256], l3[256], l4[256];
  l1[threadIdx.x] = sA; l2[threadIdx.x] = sA2; l3[threadIdx.x] = sB; l4[threadIdx.x] = sB2;
  __syncthreads();
  for (int o = 128; o > 0; o >>= 1) {
    if ((int)threadIdx.x < o) {
      l1[threadIdx.x] += l1[threadIdx.x + o];
      l2[threadIdx.x] += l2[threadIdx.x + o];
      l3[threadIdx.x] += l3[threadIdx.x + o];
      l4[threadIdx.x] += l4[threadIdx.x + o];
    }
    __syncthreads();
  }
  if (threadIdx.x == 0) {
    pA[2 * blockIdx.x] = l1[0]; pA[2 * blockIdx.x + 1] = l2[0];
    pB[2 * blockIdx.x] = l3[0]; pB[2 * blockIdx.x + 1] = l4[0];
  }
}

// ---------- LN finalize / fuse / output ----------
__device__ __forceinline__ void ln_params(double S, double S2, double M, float* mu_out, float* sc_out) {
  double mu = S / M;
  double v = S2 / M - mu * mu;
  if (!(v > 0.0)) v = 0.0;
  float fmu = (float)mu;
  float sc = 1.0f / ((float)sqrt(v) + EPS);
  if (!isfinite(fmu)) fmu = 0.0f;
  if (!isfinite(sc)) sc = 0.0f;
  *mu_out = fmu; *sc_out = sc;
}

__global__ void __launch_bounds__(256)
k_fin12(const double* __restrict__ pA, const double* __restrict__ pB, int nblk,
        const void* __restrict__ alpha, float* __restrict__ params, double M,
        const int* __restrict__ df) {
  const int fl32 = *df;
  __shared__ double l1[256], l2[256], l3[256], l4[256];
  double a = 0, b = 0, c = 0, d = 0;
  for (int j = threadIdx.x; j < nblk; j += 256) {
    a += pA[2 * j]; b += pA[2 * j + 1];
    c += pB[2 * j]; d += pB[2 * j + 1];
  }
  l1[threadIdx.x] = a; l2[threadIdx.x] = b; l3[threadIdx.x] = c; l4[threadIdx.x] = d;
  __syncthreads();
  for (int off = 128; off > 0; off >>= 1) {
    if ((int)threadIdx.x < off) {
      l1[threadIdx.x] += l1[threadIdx.x + off];
      l2[threadIdx.x] += l2[threadIdx.x + off];
      l3[threadIdx.x] += l3[threadIdx.x + off];
      l4[threadIdx.x] += l4[threadIdx.x + off];
    }
    __syncthreads();
  }
  if (threadIdx.x == 0) {
    ln_params(l1[0], l2[0], M, &params[0], &params[1]);
    ln_params(l3[0], l4[0], M, &params[2], &params[3]);
    float a0 = ldf(alpha, 0, fl32), a1 = ldf(alpha, 1, fl32);
    if (!isfinite(a0)) a0 = 0.0f;
    if (!isfinite(a1)) a1 = 0.0f;
    float mx = fmaxf(a0, a1);
    float e0 = expf(a0 - mx), e1 = expf(a1 - mx);
    float inv = 1.0f / (e0 + e1);
    params[4] = e0 * inv;
    params[5] = e1 * inv;
  }
}

__global__ void __launch_bounds__(256)
k_fin3(const double* __restrict__ pC, float* __restrict__ params, double M) {
  __shared__ double l1[256], l2[256];
  double a = 0, b = 0;
  for (int j = threadIdx.x; j < NBLK; j += 256) { a += pC[2 * j]; b += pC[2 * j + 1]; }
  l1[threadIdx.x] = a; l2[threadIdx.x] = b;
  __syncthreads();
  for (int off = 128; off > 0; off >>= 1) {
    if ((int)threadIdx.x < off) {
      l1[threadIdx.x] += l1[threadIdx.x + off];
      l2[threadIdx.x] += l2[threadIdx.x + off];
    }
    __syncthreads();
  }
  if (threadIdx.x == 0) ln_params(l1[0], l2[0], M, &params[6], &params[7]);
}

__global__ void __launch_bounds__(256)
k_fuse(const void* __restrict__ x, float* h, const float* __restrict__ g,
       const void* __restrict__ b_gcn, const void* __restrict__ b_gat,
       const void* __restrict__ gcn_nw, const void* __restrict__ gcn_nb,
       const void* __restrict__ gat_nw, const void* __restrict__ gat_nb,
       const float* __restrict__ params, double* __restrict__ pC, long n,
       const int* __restrict__ df) {
  const int fl32 = *df;
  float mu1 = params[0], sc1 = params[1], mu2 = params[2], sc2 = params[3];
  float w0 = params[4], w1 = params[5];
  double s = 0.0, s2 = 0.0;
  long stride = (long)gridDim.x * blockDim.x;
  for (long i = (long)blockIdx.x * blockDim.x + threadIdx.x; i < n; i += stride) {
    size_t c = (size_t)(i & (DIM - 1));
    float xv = ldf(x, i, fl32);
    float hv = h[i] + ldf(b_gcn, c, fl32);
    float gv = g[i] + ldf(b_gat, c, fl32);
    float go = xv + gelu_exact((hv - mu1) * sc1 * ldf(gcn_nw, c, fl32) + ldf(gcn_nb, c, fl32));
    float ao = xv + gelu_exact((gv - mu2) * sc2 * ldf(gat_nw, c, fl32) + ldf(gat_nb, c, fl32));
    float f = w0 * go + w1 * ao;
    if (!isfinite(f)) f = 0.0f;
    h[i] = f;
    s += f; s2 += (double)f * f;
  }
  __shared__ double ls[256], ls2[256];
  ls[threadIdx.x] = s; ls2[threadIdx.x] = s2;
  __syncthreads();
  for (int off = 128; off > 0; off >>= 1) {
    if ((int)threadIdx.x < off) {
      ls[threadIdx.x] += ls[threadIdx.x + off];
      ls2[threadIdx.x] += ls2[threadIdx.x + off];
    }
    __syncthreads();
  }
  if (threadIdx.x == 0) { pC[2 * blockIdx.x] = ls[0]; pC[2 * blockIdx.x + 1] = ls2[0]; }
}

__global__ void k_final(const float* __restrict__ fused, const void* __restrict__ nw,
                        const void* __restrict__ nb, const float* __restrict__ params,
                        void* __restrict__ out, long n, const int* __restrict__ df) {
  const int fl32 = *df;
  long i = (long)blockIdx.x * blockDim.x + threadIdx.x;
  if (i >= n) return;
  size_t c = (size_t)(i & (DIM - 1));
  float mu = params[6], sc = params[7];
  float r = gelu_exact((fused[i] - mu) * sc * ldf(nw, c, fl32) + ldf(nb, c, fl32));
  if (!isfinite(r)) r = 0.0f;
  if (fl32) ((float*)out)[i] = r;
  else      ((unsigned short*)out)[i] = f2us(r);
}

extern "C" void kernel_launch(void* const* d_in, const int* in_sizes, int n_in,
                              void* d_out, int out_size, void* d_ws, size_t ws_size,
                              hipStream_t stream) {
  const void* x    = d_in[0];
  const int*  ei   = (const int*)d_in[1];
  const void* ew   = d_in[2];
  const void* ea   = d_in[3];
  const void* Wg   = d_in[4];
  const void* bgcn = d_in[5];
  const void* Wl   = d_in[6];
  const void* bl   = d_in[7];
  const void* Wed  = d_in[8];
  const void* att  = d_in[9];
  const void* bgat = d_in[10];
  const void* gcn_nw = d_in[11];
  const void* gcn_nb = d_in[12];
  const void* gat_nw = d_in[13];
  const void* gat_nb = d_in[14];
  const void* out_nw = d_in[15];
  const void* out_nb = d_in[16];
  const void* alpha  = d_in[17];

  const int N = in_sizes[0] / DIM;
  const int E = in_sizes[2];
  const int* src  = ei;
  const int* dstp = ei + E;
  const size_t ND = (size_t)N * DIM;
  const int nAgg = (N + 3) / 4;

  char* ws = (char*)d_ws;
  size_t o = 0;
  auto alloc = [&](size_t bytes) { size_t r = o; o += (bytes + 255) & ~(size_t)255; return r; };
  size_t o_deg    = alloc((size_t)N * 4);
  size_t o_cnt    = alloc((size_t)N * 4);
  size_t zero_end = o;                         // [0, zero_end) memset to 0
  size_t o_off    = alloc((size_t)(N + 1) * 4);
  size_t o_h      = alloc(ND * 4);             // rank (E*4) aliases head of h
  size_t o_g      = alloc(ND * 4);
  size_t o_packed = alloc(ND * 4);             // N rows x 256 ushorts
  size_t o_csr    = alloc((size_t)E * 16);
  size_t o_wtg    = alloc(2048 * 8 * 2);
  size_t o_wtl    = alloc(2048 * 8 * 2);
  size_t o_par    = alloc(8 * 4);
  size_t o_pA     = alloc((size_t)nAgg * 2 * 8);
  size_t o_pB     = alloc((size_t)nAgg * 2 * 8);
  size_t o_pC     = alloc((size_t)NBLK * 2 * 8);
  size_t o_flag   = alloc(4);
  (void)ws_size; (void)n_in; (void)out_size;

  float* deg     = (float*)(ws + o_deg);
  int*   cnt     = (int*)(ws + o_cnt);
  int*   off     = (int*)(ws + o_off);
  float* h       = (float*)(ws + o_h);
  int*   rank    = (int*)(ws + o_h);           // alias: dead before mega writes h
  float* g       = (float*)(ws + o_g);
  unsigned short* packed = (unsigned short*)(ws + o_packed);
  int4*  csr     = (int4*)(ws + o_csr);
  unsigned short* Wtg = (unsigned short*)(ws + o_wtg);
  unsigned short* Wtl = (unsigned short*)(ws + o_wtl);
  float* params  = (float*)(ws + o_par);
  double* pA     = (double*)(ws + o_pA);
  double* pB     = (double*)(ws + o_pB);
  double* pC     = (double*)(ws + o_pC);
  int* dflag     = (int*)(ws + o_flag);

  hipMemsetAsync(ws, 0, zero_end, stream);
  k_detect<<<1, 256, 0, stream>>>((const unsigned short*)x, (long)ND, dflag);

  int ebk = (E + 255) / 256;
  k_deg_cnt<<<ebk, 256, 0, stream>>>(dstp, ew, deg, cnt, rank, E, dflag);
  k_dis<<<(N + 255) / 256, 256, 0, stream>>>(deg, N);
  k_scan<<<1, 256, 0, stream>>>(cnt, off, N, E);
  k_scatter<<<ebk, 256, 0, stream>>>(src, dstp, ew, ea, deg, off, rank, csr, E, dflag);

  k_prepW<<<8, 256, 0, stream>>>((const unsigned short*)Wg, (const unsigned short*)Wl, Wtg, Wtl);
  k_gemm<<<(N + 63) / 64, 256, 0, stream>>>(x, Wg, Wl, bl, Wtg, Wtl, packed, N, dflag);

  k_mega<<<nAgg, 256, 0, stream>>>(off, csr, packed, Wed, att, bgcn, bgat,
                                   h, g, pA, pB, N, dflag);

  k_fin12<<<1, 256, 0, stream>>>(pA, pB, nAgg, alpha, params, (double)ND, dflag);
  k_fuse<<<NBLK, 256, 0, stream>>>(x, h, g, bgcn, bgat, gcn_nw, gcn_nb, gat_nw, gat_nb,
                                   params, pC, (long)ND, dflag);
  k_fin3<<<1, 256, 0, stream>>>(pC, params, (double)ND);
  k_final<<<(int)((ND + 255) / 256), 256, 0, stream>>>(h, out_nw, out_nb, params,
                                                       d_out, (long)ND, dflag);
}

// Round 8
// 560.408 us; speedup vs baseline: 1.5197x; 1.5197x over previous
//
#include <hip/hip_runtime.h>
#include <math.h>

#define DIM 128
#define HEADS 4
#define EPS 1e-5f
#define NBLK 1024

// ---------- dtype-flex helpers ----------
__device__ __forceinline__ float us2f(unsigned short u) {
  union { unsigned int i; float f; } c; c.i = ((unsigned int)u) << 16; return c.f;
}
__device__ __forceinline__ unsigned short f2us(float f) {
  union { float ff; unsigned int i; } c; c.ff = f;
  return (unsigned short)((c.i + 0x7FFFu + ((c.i >> 16) & 1u)) >> 16);
}
__device__ __forceinline__ float ldf(const void* p, size_t i, int fl32) {
  return fl32 ? ((const float*)p)[i] : us2f(((const unsigned short*)p)[i]);
}
__device__ __forceinline__ float gelu_exact(float v) {
  return 0.5f * v * (1.0f + erff(v * 0.7071067811865475f));
}

// packed layout per row: 256 ushorts; for even c: [c*2]=xl[c], [c*2+1]=xl[c+1],
// [c*2+2]=xw[c], [c*2+3]=xw[c+1]
__device__ __forceinline__ int packed_pos(int c) { return ((c & ~1) << 1) | (c & 1); }

// ---------- dtype detection (proven) ----------
__global__ void __launch_bounds__(256)
k_detect(const unsigned short* __restrict__ x, long n, int* __restrict__ dflag) {
  long lim = n < 8192 ? n : 8192;
  int bad = 0;
  for (long i = threadIdx.x; i < lim; i += 256) {
    float v = us2f(x[i]);
    float a = fabsf(v);
    if (!(a == 0.0f || (a > 1e-30f && a < 1e3f))) bad++;
  }
  __shared__ int sb[256];
  sb[threadIdx.x] = bad;
  __syncthreads();
  for (int off = 128; off > 0; off >>= 1) {
    if ((int)threadIdx.x < off) sb[threadIdx.x] += sb[threadIdx.x + off];
    __syncthreads();
  }
  if (threadIdx.x == 0) dflag[0] = (sb[0] > 32) ? 1 : 0;
}

// ---------- CSR construction ----------
__global__ void k_deg_cnt(const int* __restrict__ dst, const void* __restrict__ ew,
                          float* __restrict__ deg, int* __restrict__ cnt,
                          int* __restrict__ rank, int E, const int* __restrict__ df) {
  const int fl32 = *df;
  int e = blockIdx.x * blockDim.x + threadIdx.x;
  if (e < E) {
    int d = dst[e];
    rank[e] = atomicAdd(&cnt[d], 1);
    float w = ldf(ew, e, fl32);
    if (isfinite(w)) atomicAdd(&deg[d], w);
  }
}

__global__ void k_dis(float* __restrict__ deg, int N) {
  int i = blockIdx.x * blockDim.x + threadIdx.x;
  if (i < N) {
    float d = deg[i];
    deg[i] = (d > 0.0f) ? rsqrtf(fmaxf(d, 1e-30f)) : 0.0f;
  }
}

__global__ void __launch_bounds__(256)
k_scan(const int* __restrict__ cnt, int* __restrict__ off, int N, int E) {
  __shared__ int part[256];
  int t = threadIdx.x;
  int chunk = (N + 255) / 256;
  int lo = t * chunk;
  int hi = lo + chunk; if (hi > N) hi = N;
  int s = 0;
  for (int i = lo; i < hi; ++i) s += cnt[i];
  part[t] = s;
  __syncthreads();
  if (t == 0) {
    int run = 0;
    for (int j = 0; j < 256; ++j) { int tmp = part[j]; part[j] = run; run += tmp; }
  }
  __syncthreads();
  int run = part[t];
  for (int i = lo; i < hi; ++i) { off[i] = run; run += cnt[i]; }
  if (t == 0) off[N] = E;
}

__global__ void k_scatter(const int* __restrict__ src, const int* __restrict__ dst,
                          const void* __restrict__ ew, const void* __restrict__ ea,
                          const float* __restrict__ dis, const int* __restrict__ off,
                          const int* __restrict__ rank, int4* __restrict__ csr,
                          int E, const int* __restrict__ df) {
  const int fl32 = *df;
  int e = blockIdx.x * blockDim.x + threadIdx.x;
  if (e >= E) return;
  int d = dst[e], s = src[e];
  int pos = off[d] + rank[e];
  float nm = dis[s] * ldf(ew, e, fl32) * dis[d];
  if (!isfinite(nm)) nm = 0.0f;
  float eav = ldf(ea, e, fl32);
  if (!isfinite(eav)) eav = 0.0f;
  csr[pos] = make_int4(s, __float_as_int(nm), __float_as_int(eav), 0);
}

// ---------- dual GEMM: proven VALU formulation, writes packed layout ----------
__global__ void __launch_bounds__(128)
k_gemm(const void* __restrict__ x, const void* __restrict__ Wg,
       const void* __restrict__ Wl, const void* __restrict__ bl,
       unsigned short* __restrict__ packed, int N, const int* __restrict__ df) {
  const int fl32 = *df;
  const int R = 8;
  __shared__ float xs[R][DIM];
  int c = threadIdx.x;
  int r0 = blockIdx.x * R;
  for (int r = 0; r < R; ++r) {
    int row = r0 + r;
    xs[r][c] = (row < N) ? ldf(x, (size_t)row * DIM + c, fl32) : 0.0f;
  }
  __syncthreads();
  float accg[R], accl[R];
  float blc = ldf(bl, c, fl32);
  #pragma unroll
  for (int r = 0; r < R; ++r) { accg[r] = 0.0f; accl[r] = blc; }
  for (int k = 0; k < DIM; ++k) {
    float wg = ldf(Wg, k * DIM + c, fl32);
    float wl = ldf(Wl, k * DIM + c, fl32);
    #pragma unroll
    for (int r = 0; r < R; ++r) {
      accg[r] = fmaf(xs[r][k], wg, accg[r]);
      accl[r] = fmaf(xs[r][k], wl, accl[r]);
    }
  }
  int pos = packed_pos(c);
  for (int r = 0; r < R; ++r) {
    int row = r0 + r;
    if (row < N) {
      float ag = accg[r], al = accl[r];
      if (!isfinite(ag)) ag = 0.0f;
      if (!isfinite(al)) al = 0.0f;
      packed[(size_t)row * 256 + pos] = f2us(al);
      packed[(size_t)row * 256 + pos + 2] = f2us(ag);
    }
  }
}

// ---------- MEGA: online softmax + GCN/GAT agg + LN stats ----------
__global__ void __launch_bounds__(256)
k_mega(const int* __restrict__ off, const int4* __restrict__ csr,
       const unsigned short* __restrict__ packed,
       const void* __restrict__ Wed, const void* __restrict__ att,
       const void* __restrict__ bgcn, const void* __restrict__ bgat,
       float* __restrict__ h, float* __restrict__ g,
       double* __restrict__ pA, double* __restrict__ pB, int N,
       const int* __restrict__ df) {
  const int fl32 = *df;
  int wid = threadIdx.x >> 6;
  int lane = threadIdx.x & 63;
  int node = blockIdx.x * 4 + wid;
  int c0 = lane * 2;
  float wd0 = ldf(Wed, c0, fl32), wd1 = ldf(Wed, c0 + 1, fl32);
  float at0 = ldf(att, c0, fl32), at1 = ldf(att, c0 + 1, fl32);
  double sA = 0.0, sA2 = 0.0, sB = 0.0, sB2 = 0.0;
  if (node < N) {
    int beg = off[node], end = off[node + 1];
    ushort4 xd = *(const ushort4*)(packed + (size_t)node * 256 + lane * 4);
    float xd0 = us2f(xd.x), xd1 = us2f(xd.y);
    float mx = -INFINITY, den = 0.f;
    float ga0 = 0.f, ga1 = 0.f, hc0 = 0.f, hc1 = 0.f;
    int4 cP = make_int4(0, 0, 0, 0);
    ushort4 vP = make_ushort4(0, 0, 0, 0);
    if (beg < end) {
      cP = csr[beg];
      vP = *(const ushort4*)(packed + (size_t)cP.x * 256 + lane * 4);
    }
    for (int i = beg; i < end; ++i) {
      int4 ce = cP; ushort4 v = vP;
      if (i + 1 < end) {
        cP = csr[i + 1];
        vP = *(const ushort4*)(packed + (size_t)cP.x * 256 + lane * 4);
      }
      float nm = __int_as_float(ce.y), eav = __int_as_float(ce.z);
      float vx = us2f(v.x), vy = us2f(v.y);
      float z0 = xd0 + vx + eav * wd0; z0 = (z0 > 0.f) ? z0 : 0.2f * z0;
      float z1 = xd1 + vy + eav * wd1; z1 = (z1 > 0.f) ? z1 : 0.2f * z1;
      float dot = z0 * at0 + z1 * at1;
      dot += __shfl_xor(dot, 1);
      dot += __shfl_xor(dot, 2);
      dot += __shfl_xor(dot, 4);
      dot += __shfl_xor(dot, 8);
      // single-expf online softmax: exactly one of {corr,w} is exp(-|dot-mx|)
      float e = __expf(-fabsf(dot - mx));   // first iter: exp(-inf) = 0
      bool up = dot > mx;
      float corr = up ? e : 1.0f;
      float w = up ? 1.0f : e;
      mx = up ? dot : mx;
      den = fmaf(den, corr, w);
      ga0 = fmaf(ga0, corr, w * vx);
      ga1 = fmaf(ga1, corr, w * vy);
      hc0 = fmaf(nm, us2f(v.z), hc0);
      hc1 = fmaf(nm, us2f(v.w), hc1);
    }
    float inv = (end > beg) ? 1.0f / (den + 1e-16f) : 0.0f;
    ga0 *= inv; ga1 *= inv;
    if (!isfinite(ga0)) ga0 = 0.0f;
    if (!isfinite(ga1)) ga1 = 0.0f;
    if (!isfinite(hc0)) hc0 = 0.0f;
    if (!isfinite(hc1)) hc1 = 0.0f;
    *(float2*)(h + (size_t)node * DIM + c0) = make_float2(hc0, hc1);
    *(float2*)(g + (size_t)node * DIM + c0) = make_float2(ga0, ga1);
    float hA0 = hc0 + ldf(bgcn, c0, fl32), hA1 = hc1 + ldf(bgcn, c0 + 1, fl32);
    float gB0 = ga0 + ldf(bgat, c0, fl32), gB1 = ga1 + ldf(bgat, c0 + 1, fl32);
    sA  = (double)hA0 + (double)hA1;
    sA2 = (double)hA0 * hA0 + (double)hA1 * hA1;
    sB  = (double)gB0 + (double)gB1;
    sB2 = (double)gB0 * gB0 + (double)gB1 * gB1;
  }
  __shared__ double l1[256], l2[256], l3[256], l4[256];
  l1[threadIdx.x] = sA; l2[threadIdx.x] = sA2; l3[threadIdx.x] = sB; l4[threadIdx.x] = sB2;
  __syncthreads();
  for (int o = 128; o > 0; o >>= 1) {
    if ((int)threadIdx.x < o) {
      l1[threadIdx.x] += l1[threadIdx.x + o];
      l2[threadIdx.x] += l2[threadIdx.x + o];
      l3[threadIdx.x] += l3[threadIdx.x + o];
      l4[threadIdx.x] += l4[threadIdx.x + o];
    }
    __syncthreads();
  }
  if (threadIdx.x == 0) {
    pA[2 * blockIdx.x] = l1[0]; pA[2 * blockIdx.x + 1] = l2[0];
    pB[2 * blockIdx.x] = l3[0]; pB[2 * blockIdx.x + 1] = l4[0];
  }
}

// ---------- LN finalize / fuse / output ----------
__device__ __forceinline__ void ln_params(double S, double S2, double M, float* mu_out, float* sc_out) {
  double mu = S / M;
  double v = S2 / M - mu * mu;
  if (!(v > 0.0)) v = 0.0;
  float fmu = (float)mu;
  float sc = 1.0f / ((float)sqrt(v) + EPS);
  if (!isfinite(fmu)) fmu = 0.0f;
  if (!isfinite(sc)) sc = 0.0f;
  *mu_out = fmu; *sc_out = sc;
}

__global__ void __launch_bounds__(256)
k_fin12(const double* __restrict__ pA, const double* __restrict__ pB, int nblk,
        const void* __restrict__ alpha, float* __restrict__ params, double M,
        const int* __restrict__ df) {
  const int fl32 = *df;
  __shared__ double l1[256], l2[256], l3[256], l4[256];
  double a = 0, b = 0, c = 0, d = 0;
  for (int j = threadIdx.x; j < nblk; j += 256) {
    a += pA[2 * j]; b += pA[2 * j + 1];
    c += pB[2 * j]; d += pB[2 * j + 1];
  }
  l1[threadIdx.x] = a; l2[threadIdx.x] = b; l3[threadIdx.x] = c; l4[threadIdx.x] = d;
  __syncthreads();
  for (int off = 128; off > 0; off >>= 1) {
    if ((int)threadIdx.x < off) {
      l1[threadIdx.x] += l1[threadIdx.x + off];
      l2[threadIdx.x] += l2[threadIdx.x + off];
      l3[threadIdx.x] += l3[threadIdx.x + off];
      l4[threadIdx.x] += l4[threadIdx.x + off];
    }
    __syncthreads();
  }
  if (threadIdx.x == 0) {
    ln_params(l1[0], l2[0], M, &params[0], &params[1]);
    ln_params(l3[0], l4[0], M, &params[2], &params[3]);
    float a0 = ldf(alpha, 0, fl32), a1 = ldf(alpha, 1, fl32);
    if (!isfinite(a0)) a0 = 0.0f;
    if (!isfinite(a1)) a1 = 0.0f;
    float mx = fmaxf(a0, a1);
    float e0 = expf(a0 - mx), e1 = expf(a1 - mx);
    float inv = 1.0f / (e0 + e1);
    params[4] = e0 * inv;
    params[5] = e1 * inv;
  }
}

__global__ void __launch_bounds__(256)
k_fin3(const double* __restrict__ pC, float* __restrict__ params, double M) {
  __shared__ double l1[256], l2[256];
  double a = 0, b = 0;
  for (int j = threadIdx.x; j < NBLK; j += 256) { a += pC[2 * j]; b += pC[2 * j + 1]; }
  l1[threadIdx.x] = a; l2[threadIdx.x] = b;
  __syncthreads();
  for (int off = 128; off > 0; off >>= 1) {
    if ((int)threadIdx.x < off) {
      l1[threadIdx.x] += l1[threadIdx.x + off];
      l2[threadIdx.x] += l2[threadIdx.x + off];
    }
    __syncthreads();
  }
  if (threadIdx.x == 0) ln_params(l1[0], l2[0], M, &params[6], &params[7]);
}

__global__ void __launch_bounds__(256)
k_fuse(const void* __restrict__ x, float* h, const float* __restrict__ g,
       const void* __restrict__ b_gcn, const void* __restrict__ b_gat,
       const void* __restrict__ gcn_nw, const void* __restrict__ gcn_nb,
       const void* __restrict__ gat_nw, const void* __restrict__ gat_nb,
       const float* __restrict__ params, double* __restrict__ pC, long n,
       const int* __restrict__ df) {
  const int fl32 = *df;
  float mu1 = params[0], sc1 = params[1], mu2 = params[2], sc2 = params[3];
  float w0 = params[4], w1 = params[5];
  double s = 0.0, s2 = 0.0;
  long stride = (long)gridDim.x * blockDim.x;
  for (long i = (long)blockIdx.x * blockDim.x + threadIdx.x; i < n; i += stride) {
    size_t c = (size_t)(i & (DIM - 1));
    float xv = ldf(x, i, fl32);
    float hv = h[i] + ldf(b_gcn, c, fl32);
    float gv = g[i] + ldf(b_gat, c, fl32);
    float go = xv + gelu_exact((hv - mu1) * sc1 * ldf(gcn_nw, c, fl32) + ldf(gcn_nb, c, fl32));
    float ao = xv + gelu_exact((gv - mu2) * sc2 * ldf(gat_nw, c, fl32) + ldf(gat_nb, c, fl32));
    float f = w0 * go + w1 * ao;
    if (!isfinite(f)) f = 0.0f;
    h[i] = f;
    s += f; s2 += (double)f * f;
  }
  __shared__ double ls[256], ls2[256];
  ls[threadIdx.x] = s; ls2[threadIdx.x] = s2;
  __syncthreads();
  for (int off = 128; off > 0; off >>= 1) {
    if ((int)threadIdx.x < off) {
      ls[threadIdx.x] += ls[threadIdx.x + off];
      ls2[threadIdx.x] += ls2[threadIdx.x + off];
    }
    __syncthreads();
  }
  if (threadIdx.x == 0) { pC[2 * blockIdx.x] = ls[0]; pC[2 * blockIdx.x + 1] = ls2[0]; }
}

__global__ void k_final(const float* __restrict__ fused, const void* __restrict__ nw,
                        const void* __restrict__ nb, const float* __restrict__ params,
                        void* __restrict__ out, long n, const int* __restrict__ df) {
  const int fl32 = *df;
  long i = (long)blockIdx.x * blockDim.x + threadIdx.x;
  if (i >= n) return;
  size_t c = (size_t)(i & (DIM - 1));
  float mu = params[6], sc = params[7];
  float r = gelu_exact((fused[i] - mu) * sc * ldf(nw, c, fl32) + ldf(nb, c, fl32));
  if (!isfinite(r)) r = 0.0f;
  if (fl32) ((float*)out)[i] = r;
  else      ((unsigned short*)out)[i] = f2us(r);
}

extern "C" void kernel_launch(void* const* d_in, const int* in_sizes, int n_in,
                              void* d_out, int out_size, void* d_ws, size_t ws_size,
                              hipStream_t stream) {
  const void* x    = d_in[0];
  const int*  ei   = (const int*)d_in[1];
  const void* ew   = d_in[2];
  const void* ea   = d_in[3];
  const void* Wg   = d_in[4];
  const void* bgcn = d_in[5];
  const void* Wl   = d_in[6];
  const void* bl   = d_in[7];
  const void* Wed  = d_in[8];
  const void* att  = d_in[9];
  const void* bgat = d_in[10];
  const void* gcn_nw = d_in[11];
  const void* gcn_nb = d_in[12];
  const void* gat_nw = d_in[13];
  const void* gat_nb = d_in[14];
  const void* out_nw = d_in[15];
  const void* out_nb = d_in[16];
  const void* alpha  = d_in[17];

  const int N = in_sizes[0] / DIM;
  const int E = in_sizes[2];
  const int* src  = ei;
  const int* dstp = ei + E;
  const size_t ND = (size_t)N * DIM;
  const int nAgg = (N + 3) / 4;

  char* ws = (char*)d_ws;
  size_t o = 0;
  auto alloc = [&](size_t bytes) { size_t r = o; o += (bytes + 255) & ~(size_t)255; return r; };
  size_t o_deg    = alloc((size_t)N * 4);
  size_t o_cnt    = alloc((size_t)N * 4);
  size_t zero_end = o;                         // [0, zero_end) memset to 0
  size_t o_off    = alloc((size_t)(N + 1) * 4);
  size_t o_h      = alloc(ND * 4);             // rank (E*4) aliases head of h
  size_t o_g      = alloc(ND * 4);
  size_t o_packed = alloc(ND * 4);             // N rows x 256 ushorts
  size_t o_csr    = alloc((size_t)E * 16);
  size_t o_par    = alloc(8 * 4);
  size_t o_pA     = alloc((size_t)nAgg * 2 * 8);
  size_t o_pB     = alloc((size_t)nAgg * 2 * 8);
  size_t o_pC     = alloc((size_t)NBLK * 2 * 8);
  size_t o_flag   = alloc(4);
  (void)ws_size; (void)n_in; (void)out_size;

  float* deg     = (float*)(ws + o_deg);
  int*   cnt     = (int*)(ws + o_cnt);
  int*   off     = (int*)(ws + o_off);
  float* h       = (float*)(ws + o_h);
  int*   rank    = (int*)(ws + o_h);           // alias: dead before mega writes h
  float* g       = (float*)(ws + o_g);
  unsigned short* packed = (unsigned short*)(ws + o_packed);
  int4*  csr     = (int4*)(ws + o_csr);
  float* params  = (float*)(ws + o_par);
  double* pA     = (double*)(ws + o_pA);
  double* pB     = (double*)(ws + o_pB);
  double* pC     = (double*)(ws + o_pC);
  int* dflag     = (int*)(ws + o_flag);

  hipMemsetAsync(ws, 0, zero_end, stream);
  k_detect<<<1, 256, 0, stream>>>((const unsigned short*)x, (long)ND, dflag);

  int ebk = (E + 255) / 256;
  k_deg_cnt<<<ebk, 256, 0, stream>>>(dstp, ew, deg, cnt, rank, E, dflag);
  k_dis<<<(N + 255) / 256, 256, 0, stream>>>(deg, N);
  k_scan<<<1, 256, 0, stream>>>(cnt, off, N, E);
  k_scatter<<<ebk, 256, 0, stream>>>(src, dstp, ew, ea, deg, off, rank, csr, E, dflag);

  k_gemm<<<(N + 7) / 8, 128, 0, stream>>>(x, Wg, Wl, bl, packed, N, dflag);

  k_mega<<<nAgg, 256, 0, stream>>>(off, csr, packed, Wed, att, bgcn, bgat,
                                   h, g, pA, pB, N, dflag);

  k_fin12<<<1, 256, 0, stream>>>(pA, pB, nAgg, alpha, params, (double)ND, dflag);
  k_fuse<<<NBLK, 256, 0, stream>>>(x, h, g, bgcn, bgat, gcn_nw, gcn_nb, gat_nw, gat_nb,
                                   params, pC, (long)ND, dflag);
  k_fin3<<<1, 256, 0, stream>>>(pC, params, (double)ND);
  k_final<<<(int)((ND + 255) / 256), 256, 0, stream>>>(h, out_nw, out_nb, params,
                                                       d_out, (long)ND, dflag);
}